// Round 5
// baseline (35.767 us; speedup 1.0000x reference)
//
#include <hip/hip_runtime.h>
#include <hip/hip_bf16.h>

// Y[b,e,k,j] = sum_i X[b, ind[b,e,k], i] * W[e,i,j]
// X:[B,T,I] f32, ind:[B,E,K] int32, W:[E,I,J] f32 -> Y:[B,E,K,J] f32
#define B_ 8
#define T_ 8192
#define I_ 128
#define E_ 16
#define J_ 128
#define K_ 1024
#define ROWS 64   // k-rows per tile; 2 tiles per block

typedef unsigned short u16;
typedef unsigned int   u32;
typedef __attribute__((ext_vector_type(8))) short s8v;   // 8 bf16 = 4 VGPRs
typedef __attribute__((ext_vector_type(4))) float f4v;   // MFMA accumulator

__device__ __forceinline__ u16 f2bf(float f) {
    union { __hip_bfloat16 h; u16 u; } v;
    v.h = __float2bfloat16(f);          // RNE, compiles to v_cvt_pk_bf16_f32 pairs
    return v.u;
}

__device__ __forceinline__ void gload_lds16(const void* g, void* l) {
    __builtin_amdgcn_global_load_lds(
        (const __attribute__((address_space(1))) u32*)g,
        (__attribute__((address_space(3))) u32*)l, 16, 0, 0);
}

// ---- Prepass: write PRE-SWIZZLED bf16 W^T image per expert ----
// Image chunk c (16B): j = c>>4, i0 = (c&15)*8, holds bf16 W[e][i0..i0+7][j] at
// byte offset (c*16) ^ ((j&7)<<4). 64 blocks = (e, j-quarter), coalesced.
__global__ void convert_wt(const float* __restrict__ W, u16* __restrict__ Wt) {
    __shared__ float Wf[I_ * 33];        // [i][jl], jl=0..31, padded
    const int bid = blockIdx.x;          // e*4 + jq
    const int e   = bid >> 2;
    const int j0  = (bid & 3) * 32;
    const int t   = threadIdx.x;
    const float* We = W + (size_t)e * (I_ * J_);
#pragma unroll
    for (int u = 0; u < 4; ++u) {
        const int f4 = t + 256 * u;      // 0..1023
        const int i  = f4 >> 3;
        const int c  = f4 & 7;
        const float4 v = *reinterpret_cast<const float4*>(We + (size_t)i * J_ + j0 + c * 4);
        float* p = &Wf[i * 33 + c * 4];
        p[0] = v.x; p[1] = v.y; p[2] = v.z; p[3] = v.w;
    }
    __syncthreads();
    char* img = (char*)Wt + (size_t)e * (I_ * J_ * 2);
#pragma unroll
    for (int u2 = 0; u2 < 2; ++u2) {
        const int c  = t + 256 * u2;     // 0..511
        const int jl = c >> 4;
        const int j  = j0 + jl;
        const int i0 = (c & 15) * 8;
        s8v o;
#pragma unroll
        for (int u = 0; u < 8; ++u)
            o[u] = (short)f2bf(Wf[(i0 + u) * 33 + jl]);
        const int cimg = j * 16 + (c & 15);
        *reinterpret_cast<s8v*>(img + ((cimg * 16) ^ ((j & 7) << 4))) = o;
    }
}

// ---- Main: gather + bf16 MFMA GEMM, 2 k-tiles/block, T14 pipeline ----
// 256 threads. LDS: WsT 32KB + Xs 16KB = 48KB -> 3 blocks/CU (12 waves/CU).
template<bool PRE>
__global__ __launch_bounds__(256, 3)
void gather_mfma(const float* __restrict__ X, const int* __restrict__ ind,
                 const void* __restrict__ Wsrc, float* __restrict__ Y) {
    __shared__ u16 WsT[I_ * J_];
    __shared__ u16 Xs[ROWS * I_];

    const int t    = threadIdx.x;
    const int wave = t >> 6;
    const int lane = t & 63;

    const int h  = blockIdx.x & 7;       // 8 double-tiles per (b,e)
    const int be = blockIdx.x >> 3;
    const int e  = be & (E_ - 1);
    const int b  = be >> 4;
    const int k0 = h * (2 * ROWS);

    const int r   = t >> 2;              // row 0..63 (4 threads/row)
    const int q4  = t & 3;               // 32-float quarter of the row
    const int sxr = (r & 7) << 4;
    char* xrow = (char*)Xs + r * 256;

    // Issue index loads for BOTH tiles first (removes load-dependent chain later)
    const int idx0 = ind[(size_t)be * K_ + k0 + r];
    const int idx1 = ind[(size_t)be * K_ + k0 + ROWS + r];

    // ---- Stage WsT (async, linear copy of pre-swizzled image) ----
    if (PRE) {
        const char* Wimg = (const char*)Wsrc + (size_t)e * 32768;
#pragma unroll
        for (int u = 0; u < 8; ++u) {
            const int off = (wave * 8 + u) * 1024;   // wave-uniform LDS dest
            gload_lds16(Wimg + off + lane * 16, (char*)WsT + off);
        }
    } else {
        const float* We = (const float*)Wsrc + (size_t)e * (I_ * J_);
#pragma unroll
        for (int u = 0; u < 16; ++u) {
            const int f4i = t + 256 * u;
            const int i   = f4i >> 5;
            const int j0  = (f4i & 31) * 4;
            const float4 w4 = reinterpret_cast<const float4*>(We)[f4i];
            const float ws[4] = {w4.x, w4.y, w4.z, w4.w};
#pragma unroll
            for (int q = 0; q < 4; ++q) {
                const int j = j0 + q;
                *(u16*)((char*)WsT + ((j * 256 + i * 2) ^ ((j & 7) << 4))) = f2bf(ws[q]);
            }
        }
    }

    float4 v[8];
    auto pack_write = [&]() {
#pragma unroll
        for (int u = 0; u < 4; ++u) {
            const float4 a = v[2 * u], c = v[2 * u + 1];
            s8v o;
            o[0] = (short)f2bf(a.x); o[1] = (short)f2bf(a.y);
            o[2] = (short)f2bf(a.z); o[3] = (short)f2bf(a.w);
            o[4] = (short)f2bf(c.x); o[5] = (short)f2bf(c.y);
            o[6] = (short)f2bf(c.z); o[7] = (short)f2bf(c.w);
            *reinterpret_cast<s8v*>(xrow + ((q4 * 64 + u * 16) ^ sxr)) = o;
        }
    };

    // ---- Stage tile 0 ----
    {
        const float4* Xr = reinterpret_cast<const float4*>(X + ((size_t)b * T_ + idx0) * I_) + q4 * 8;
#pragma unroll
        for (int u = 0; u < 8; ++u) v[u] = Xr[u];
        pack_write();
    }
    __syncthreads();     // W copy + tile0 visible

    // ---- Compute setup (swapped operands: A = W^T (m=j), B = X (n=k-row)) ----
    const int rh  = wave >> 1;
    const int jh  = wave & 1;
    const int g   = lane >> 4;
    const int l15 = lane & 15;
    const int sx  = (lane & 7) << 4;
    const char* xb = (const char*)Xs  + (size_t)(rh * 32 + l15) * 256;
    const char* wb = (const char*)WsT + (size_t)(jh * 64 + l15) * 256;

    auto compute_store = [&](int kbase) {
        f4v acc[2][4];
#pragma unroll
        for (int tr = 0; tr < 2; ++tr)
#pragma unroll
            for (int nj = 0; nj < 4; ++nj)
#pragma unroll
                for (int rr = 0; rr < 4; ++rr) acc[tr][nj][rr] = 0.f;
#pragma unroll
        for (int s = 0; s < 4; ++s) {
            const int off = (s * 64 + g * 16) ^ sx;
            const s8v x0 = *reinterpret_cast<const s8v*>(xb + off);
            const s8v x1 = *reinterpret_cast<const s8v*>(xb + 16 * 256 + off);
#pragma unroll
            for (int nj = 0; nj < 4; ++nj) {
                const s8v wf = *reinterpret_cast<const s8v*>(wb + nj * 16 * 256 + off);
                acc[0][nj] = __builtin_amdgcn_mfma_f32_16x16x32_bf16(wf, x0, acc[0][nj], 0, 0, 0);
                acc[1][nj] = __builtin_amdgcn_mfma_f32_16x16x32_bf16(wf, x1, acc[1][nj], 0, 0, 0);
            }
        }
        // Y[k = rh*32+tr*16+l15][j = jh*64+g*4+nj*16] : float4 along j
        float* Yb = Y + ((size_t)be * K_ + kbase) * J_;
#pragma unroll
        for (int tr = 0; tr < 2; ++tr) {
            float* rowp = Yb + (size_t)(rh * 32 + tr * 16 + l15) * J_ + jh * 64 + g * 4;
#pragma unroll
            for (int nj = 0; nj < 4; ++nj)
                *reinterpret_cast<f4v*>(rowp + nj * 16) = acc[tr][nj];
        }
    };

    // ---- Tile 0: prefetch tile 1 (T14: issue-early), compute, store ----
    {
        const float4* Xr = reinterpret_cast<const float4*>(X + ((size_t)b * T_ + idx1) * I_) + q4 * 8;
#pragma unroll
        for (int u = 0; u < 8; ++u) v[u] = Xr[u];   // in flight across compute
    }
    compute_store(k0);
    __syncthreads();     // all waves done reading Xs (tile0)
    pack_write();        // write-late: tile1 into Xs
    __syncthreads();
    compute_store(k0 + ROWS);
}

extern "C" void kernel_launch(void* const* d_in, const int* in_sizes, int n_in,
                              void* d_out, int out_size, void* d_ws, size_t ws_size,
                              hipStream_t stream) {
    (void)in_sizes; (void)n_in; (void)out_size;
    const float* X   = (const float*)d_in[0];
    const int*   ind = (const int*)d_in[1];
    const float* W   = (const float*)d_in[2];
    float*       Y   = (float*)d_out;

    const size_t wt_bytes = (size_t)E_ * I_ * J_ * sizeof(u16);  // 512 KB
    const int grid = B_ * E_ * (K_ / ROWS) / 2;                   // 1024

    if (ws_size >= wt_bytes && d_ws != nullptr) {
        u16* Wt = (u16*)d_ws;
        hipLaunchKernelGGL(convert_wt, dim3(E_ * 4), dim3(256), 0, stream, W, Wt);
        hipLaunchKernelGGL((gather_mfma<true>), dim3(grid), dim3(256), 0, stream,
                           X, ind, (const void*)Wt, Y);
    } else {
        hipLaunchKernelGGL((gather_mfma<false>), dim3(grid), dim3(256), 0, stream,
                           X, ind, (const void*)W, Y);
    }
}